// Round 3
// baseline (507.544 us; speedup 1.0000x reference)
//
#include <hip/hip_runtime.h>

typedef __attribute__((ext_vector_type(8))) short bf16x8;
typedef __attribute__((ext_vector_type(4))) float f32x4;

#define NROWS   65536
#define NSLICE  8
#define SLICESZ 4160
#define SETSZ   (NSLICE*SLICESZ)   // 33280 floats per iteration set
#define EPSV    1e-8f
#define RPITCH  264                 // rLT row pitch in halfwords (+8 pad)

#define KB      256                 // kmeans blocks per launch (1/CU)
#define SCHUNK  1048576             // float4 per array streamed per launch (16 per thread)

// ---- ws layout (float offsets) ----
#define WS_DEC   0
#define WS_LOSS  1
#define WS_SETS  16                          // 9 sets (iters 0..8 write)
#define WS_X2    (WS_SETS + 9*SETSZ)         // 299536
#define WS_ENCB  (WS_X2 + NROWS)             // 365072
#define WS_EBF   (WS_ENCB + 2097152)
#define WS_END   (WS_EBF + 2097152)          // ~18.3 MB

static __device__ __forceinline__ unsigned short f2bf(float f) {
    union { float f; unsigned u; } v; v.f = f;
    unsigned u = v.u + 0x7fffu + ((v.u >> 16) & 1u);
    return (unsigned short)(u >> 16);
}
static __device__ __forceinline__ float bf2f(unsigned short h) {
    union { unsigned u; float f; } v; v.u = ((unsigned)h) << 16; return v.f;
}
static __device__ __forceinline__ uint4 pack8(const unsigned short* h) {
    uint4 o;
    o.x = h[0] | ((unsigned)h[1] << 16);
    o.y = h[2] | ((unsigned)h[3] << 16);
    o.z = h[4] | ((unsigned)h[5] << 16);
    o.w = h[6] | ((unsigned)h[7] << 16);
    return o;
}

// ---------------------------------------------------------------------------
// Wave-granularity decoder-loss streaming state: 4 batches of 4 X/D f32x4
// pairs (8 NT loads = 32 VGPRs in flight).  issue(b) at one phase boundary,
// consume one phase later — HBM latency hides under an entire kmeans phase.
// ---------------------------------------------------------------------------
struct StreamSt {
    const f32x4* X;
    const f32x4* D;
    size_t   base;
    f32x4    x[4], d[4];
    float    s0, s1, s2, s3;
    bool     on;
};

static __device__ __forceinline__ void stream_issue(StreamSt& st, int b) {
    if (!st.on) return;
    #pragma unroll
    for (int j = 0; j < 4; ++j) {
        size_t off = st.base + (size_t)(b * 4 + j) * 65536;
        st.x[j] = __builtin_nontemporal_load(&st.X[off]);
        st.d[j] = __builtin_nontemporal_load(&st.D[off]);
    }
}
static __device__ __forceinline__ void stream_consume(StreamSt& st) {
    if (!st.on) return;
    #pragma unroll
    for (int j = 0; j < 4; ++j) {
        f32x4 a = st.x[j] - st.d[j];
        st.s0 = fmaf(a.x, a.x, st.s0);
        st.s1 = fmaf(a.y, a.y, st.s1);
        st.s2 = fmaf(a.z, a.z, st.s2);
        st.s3 = fmaf(a.w, a.w, st.s3);
    }
}

// ---------------------------------------------------------------------------
// prep0: enc f32 -> encB (bf16 row-major), encBfrag (phase-2 B fragment
// order), x2[row] = |bf16(enc_row)|^2.  Grid 1024 x 256, 64 rows/block.
// ---------------------------------------------------------------------------
__global__ __launch_bounds__(256) void prep0(
    const float* __restrict__ enc, unsigned* __restrict__ encB,
    uint4* __restrict__ encBfrag, float* __restrict__ x2)
{
    __shared__ unsigned short L[64 * 64];
    int t = threadIdx.x;
    int rl = t >> 2, part = t & 3;
    int row = blockIdx.x * 64 + rl;
    const float4* src = (const float4*)(enc + (size_t)row * 64 + part * 16);
    unsigned short hv[16];
    float ss = 0.f;
    #pragma unroll
    for (int i = 0; i < 4; ++i) {
        float4 v = src[i];
        unsigned short a = f2bf(v.x), b = f2bf(v.y), c = f2bf(v.z), d = f2bf(v.w);
        hv[i*4+0] = a; hv[i*4+1] = b; hv[i*4+2] = c; hv[i*4+3] = d;
        float fa = bf2f(a), fb = bf2f(b), fc = bf2f(c), fd = bf2f(d);
        ss = fmaf(fa, fa, fmaf(fb, fb, fmaf(fc, fc, fmaf(fd, fd, ss))));
    }
    unsigned* dst = encB + ((size_t)row * 64 + part * 16) / 2;
    #pragma unroll
    for (int i = 0; i < 8; ++i) dst[i] = (unsigned)hv[2*i] | ((unsigned)hv[2*i+1] << 16);
    #pragma unroll
    for (int i = 0; i < 16; ++i) L[rl * 64 + part * 16 + i] = hv[i];
    ss += __shfl_xor(ss, 1, 64);
    ss += __shfl_xor(ss, 2, 64);
    if (part == 0) x2[row] = ss;
    __syncthreads();
    for (int e = t; e < 512; e += 256) {
        int rbl = e >> 8, dt = (e >> 6) & 3, lane = e & 63;
        int q = lane >> 4, c = lane & 15;
        unsigned short hw[8];
        #pragma unroll
        for (int j = 0; j < 8; ++j)
            hw[j] = L[(rbl * 32 + q * 8 + j) * 64 + dt * 16 + c];
        encBfrag[(size_t)blockIdx.x * 512 + e] = pack8(hw);
    }
}

// ---------------------------------------------------------------------------
// Fused k-means iteration + intra-block decoder-loss streaming.
// Every kmeans block streams its own 131 KB share of X/Dec in 4 in-flight
// batches issued at phase boundaries (T14 async-split): the same waves own
// both instruction streams, so overlap is guaranteed (block-level fusion in
// rounds 1-2 showed ~zero overlap: +12.6us/launch = the serialized DRAM
// time of the streamed bytes).
// ---------------------------------------------------------------------------
__global__ __launch_bounds__(256, 1) void kmeans_main(
    const bf16x8* __restrict__ encB8, const bf16x8* __restrict__ encBfrag8,
    const float* __restrict__ enc, const float* __restrict__ prev_set,
    float* __restrict__ cur_set, const float* __restrict__ x2,
    float* __restrict__ loss_sum, int mode,
    const f32x4* __restrict__ Xs, const f32x4* __restrict__ Ds,
    float* __restrict__ dec_sum, int itchunk)
{
    __shared__ union {
        unsigned short CsBf[4096];        // prologue: bf16 C[k][d]
        unsigned short rLT[64 * RPITCH];  // phase 1/2: r^T  [k][row_local]
    } U;
    __shared__ float x2L[256];
    __shared__ float c2L[64];
    __shared__ float rslL[64];
    __shared__ float rsumL[64];
    __shared__ float lredL[4];

    const int t = threadIdx.x;
    const int wave = t >> 6, lane = t & 63, q = lane >> 4, c = lane & 15;
    const int blockR0 = blockIdx.x * 256;

    // ---- streaming state; batch 0 issued before anything else ----
    StreamSt st;
    st.X = Xs; st.D = Ds;
    st.base = (size_t)itchunk * SCHUNK + (size_t)blockIdx.x * 256 + t;
    st.s0 = st.s1 = st.s2 = st.s3 = 0.f;
    st.on = (itchunk < 8);
    stream_issue(st, 0);                       // in flight across prologue

    // ---- prologue ----
    x2L[t] = x2[blockR0 + t];
    if (t < 64) {
        rsumL[t] = 0.f;
        float v = 0.f;
        if (mode != 0) {
            #pragma unroll
            for (int sl = 0; sl < NSLICE; ++sl)
                v += prev_set[sl * SLICESZ + 4096 + t];
        }
        rslL[t] = 1.f / (v + EPSV);
    }
    __syncthreads();

    float c2part[4];
    #pragma unroll
    for (int j = 0; j < 4; ++j) {
        int v4 = t + j * 256;      // f32x4 index into C (1024 total)
        int row = v4 >> 4;
        float vx, vy, vz, vw;
        if (mode == 0) {
            f32x4 e = ((const f32x4*)enc)[v4];
            vx = e.x; vy = e.y; vz = e.z; vw = e.w;
        } else {
            float sx = 0.f, sy = 0.f, sz = 0.f, sw = 0.f;
            #pragma unroll
            for (int sl = 0; sl < NSLICE; ++sl) {
                f32x4 u = ((const f32x4*)(prev_set + (size_t)sl * SLICESZ))[v4];
                sx += u.x; sy += u.y; sz += u.z; sw += u.w;
            }
            float inv = rslL[row];
            vx = sx * inv; vy = sy * inv; vz = sz * inv; vw = sw * inv;
        }
        ushort4 h;
        h.x = f2bf(vx); h.y = f2bf(vy); h.z = f2bf(vz); h.w = f2bf(vw);
        ((ushort4*)U.CsBf)[v4] = h;
        float fx = bf2f(h.x), fy = bf2f(h.y), fz = bf2f(h.z), fw = bf2f(h.w);
        c2part[j] = fmaf(fx, fx, fmaf(fy, fy, fmaf(fz, fz, fw * fw)));
    }
    #pragma unroll
    for (int j = 0; j < 4; ++j) {
        float p = c2part[j];
        p += __shfl_xor(p, 1, 64); p += __shfl_xor(p, 2, 64);
        p += __shfl_xor(p, 4, 64); p += __shfl_xor(p, 8, 64);
        if ((lane & 15) == 0) c2L[j * 16 + (t >> 4)] = p;
    }
    __syncthreads();

    bf16x8 bfr[2][4];
    #pragma unroll
    for (int kk2 = 0; kk2 < 2; ++kk2)
        #pragma unroll
        for (int nt = 0; nt < 4; ++nt)
            bfr[kk2][nt] = *(const bf16x8*)&U.CsBf[(nt * 16 + c) * 64 + kk2 * 32 + q * 8];
    float c2f[4];
    #pragma unroll
    for (int nt = 0; nt < 4; ++nt) c2f[nt] = c2L[nt * 16 + c];
    __syncthreads();   // CsBf dead; U.rLT may now be written

    // batch 1 in flight across phase-1 pass 0; fold batch 0
    stream_issue(st, 1);
    stream_consume(st);

    // ---- phase 1 (+softmax), 2 passes of 128 rows ----
    const f32x4 z4 = {0.f, 0.f, 0.f, 0.f};
    float rs[4] = {0.f, 0.f, 0.f, 0.f};
    float lossacc = 0.f;
    #pragma unroll
    for (int p = 0; p < 2; ++p) {
        bf16x8 a2f[4];
        #pragma unroll
        for (int sub = 0; sub < 2; ++sub) {
            int arow = blockR0 + p * 128 + wave * 32 + 8 * (c >> 2) + sub * 4 + (c & 3);
            const bf16x8* ap = encB8 + (size_t)arow * 8 + q;
            bf16x8 a0 = ap[0], a1 = ap[4];
            f32x4 accf[4];
            #pragma unroll
            for (int nt = 0; nt < 4; ++nt) {
                f32x4 s = __builtin_amdgcn_mfma_f32_16x16x32_bf16(a0, bfr[0][nt], z4, 0, 0, 0);
                accf[nt]  = __builtin_amdgcn_mfma_f32_16x16x32_bf16(a1, bfr[1][nt], s,  0, 0, 0);
            }
            #pragma unroll
            for (int reg = 0; reg < 4; ++reg) {
                int rloc = p * 128 + wave * 32 + 8 * q + sub * 4 + reg;
                float x2r = x2L[rloc];
                float d2[4], mn = 3.4e38f;
                #pragma unroll
                for (int nt = 0; nt < 4; ++nt) {
                    float v = fmaxf(x2r + c2f[nt] - 2.f * accf[nt][reg], 0.f);
                    d2[nt] = v; mn = fminf(mn, v);
                }
                mn = fminf(mn, __shfl_xor(mn, 1, 64));
                mn = fminf(mn, __shfl_xor(mn, 2, 64));
                mn = fminf(mn, __shfl_xor(mn, 4, 64));
                mn = fminf(mn, __shfl_xor(mn, 8, 64));
                float e[4], s = 0.f, swd = 0.f;
                #pragma unroll
                for (int nt = 0; nt < 4; ++nt) {
                    float ev = __expf(mn - d2[nt]);
                    e[nt] = ev; s += ev; swd = fmaf(ev, d2[nt], swd);
                }
                s   += __shfl_xor(s, 1, 64);   swd += __shfl_xor(swd, 1, 64);
                s   += __shfl_xor(s, 2, 64);   swd += __shfl_xor(swd, 2, 64);
                s   += __shfl_xor(s, 4, 64);   swd += __shfl_xor(swd, 4, 64);
                s   += __shfl_xor(s, 8, 64);   swd += __shfl_xor(swd, 8, 64);
                float inv = 1.f / s;
                if (mode == 2 && c == 0) lossacc += swd * inv;
                #pragma unroll
                for (int nt = 0; nt < 4; ++nt) {
                    float rv = e[nt] * inv;
                    rs[nt] += rv;
                    a2f[nt][sub * 4 + reg] = (short)f2bf(rv);
                }
            }
        }
        if (mode != 2) {
            #pragma unroll
            for (int nt = 0; nt < 4; ++nt)
                *(bf16x8*)&U.rLT[(nt * 16 + c) * RPITCH + p * 128 + wave * 32 + 8 * q] = a2f[nt];
        }
        if (p == 0) {                 // batch 2 in flight across pass 1
            stream_issue(st, 2);
            stream_consume(st);
        }
    }

    // batch 3 in flight across phase 2; fold batch 2
    stream_issue(st, 3);
    stream_consume(st);

    if (mode != 2) {
        #pragma unroll
        for (int nt = 0; nt < 4; ++nt) {
            float v = rs[nt];
            v += __shfl_xor(v, 16, 64);
            v += __shfl_xor(v, 32, 64);
            if (q == 0) atomicAdd(&rsumL[nt * 16 + c], v);
        }
        __syncthreads();   // rLT visible, rsumL complete

        // ---- phase 2: wave owns k-rows mt=wave, all 8 row-subtiles ----
        const int mt = wave;
        f32x4 cacc[4];
        #pragma unroll
        for (int dt = 0; dt < 4; ++dt) cacc[dt] = z4;
        #pragma unroll
        for (int kk = 0; kk < 8; ++kk) {
            bf16x8 aA = *(const bf16x8*)&U.rLT[(mt * 16 + c) * RPITCH + kk * 32 + q * 8];
            #pragma unroll
            for (int dt = 0; dt < 4; ++dt) {
                bf16x8 bB = encBfrag8[((size_t)(blockIdx.x * 8 + kk) * 4 + dt) * 64 + lane];
                cacc[dt] = __builtin_amdgcn_mfma_f32_16x16x32_bf16(aA, bB, cacc[dt], 0, 0, 0);
            }
        }
        float* slice = cur_set + (size_t)(blockIdx.x & (NSLICE - 1)) * SLICESZ;
        #pragma unroll
        for (int dt = 0; dt < 4; ++dt)
            #pragma unroll
            for (int reg = 0; reg < 4; ++reg)
                atomicAdd(&slice[(mt * 16 + q * 4 + reg) * 64 + dt * 16 + c],
                          cacc[dt][reg]);
        if (t < 64) atomicAdd(&slice[4096 + t], rsumL[t]);
    } else {
        #pragma unroll
        for (int off = 32; off; off >>= 1) lossacc += __shfl_down(lossacc, off, 64);
        if (lane == 0) lredL[wave] = lossacc;
        __syncthreads();
        if (t == 0) atomicAdd(loss_sum, lredL[0] + lredL[1] + lredL[2] + lredL[3]);
    }

    // ---- fold last batch, one dec_sum atomic per wave ----
    if (st.on) {
        stream_consume(st);
        float s = (st.s0 + st.s1) + (st.s2 + st.s3);
        #pragma unroll
        for (int off = 32; off; off >>= 1) s += __shfl_down(s, off, 64);
        if (lane == 0) atomicAdd(dec_sum, s);
    }
}

// ---------------------------------------------------------------------------
__global__ void finalize_kernel(const float* __restrict__ dec_sum,
                                const float* __restrict__ loss_sum,
                                float* __restrict__ out)
{
    out[0] = dec_sum[0] * (1.f / (65536.f * 512.f))
           + 0.001f * (loss_sum[0] * (1.f / 65536.f));
}

// ---------------------------------------------------------------------------
extern "C" void kernel_launch(void* const* d_in, const int* in_sizes, int n_in,
                              void* d_out, int out_size, void* d_ws, size_t ws_size,
                              hipStream_t stream)
{
    const float* X   = (const float*)d_in[0];
    const float* enc = (const float*)d_in[1];
    const float* dec = (const float*)d_in[2];

    float* ws = (float*)d_ws;
    float* dec_sum  = ws + WS_DEC;
    float* loss_sum = ws + WS_LOSS;
    float* sets = ws + WS_SETS;
    float* x2   = ws + WS_X2;
    unsigned* encB  = (unsigned*)(ws + WS_ENCB);
    uint4* encBfrag = (uint4*)(ws + WS_EBF);

    hipMemsetAsync(d_ws, 0, (size_t)WS_X2 * sizeof(float), stream);

    prep0<<<dim3(1024), dim3(256), 0, stream>>>(enc, encB, encBfrag, x2);

    const bf16x8* encB8 = (const bf16x8*)encB;
    const bf16x8* eBf8  = (const bf16x8*)encBfrag;

    for (int it = 0; it < 10; ++it) {
        int mode = (it == 0) ? 0 : ((it == 9) ? 2 : 1);
        const float* prev = (it == 0) ? sets : sets + (size_t)(it - 1) * SETSZ;
        float* cur = (it < 9) ? sets + (size_t)it * SETSZ : sets;
        kmeans_main<<<dim3(KB), dim3(256), 0, stream>>>(
            encB8, eBf8, enc, prev, cur, x2, loss_sum, mode,
            (const f32x4*)X, (const f32x4*)dec, dec_sum, it);
    }
    finalize_kernel<<<1, 1, 0, stream>>>(dec_sum, loss_sum, (float*)d_out);
}

// Round 5
// 462.704 us; speedup vs baseline: 1.0969x; 1.0969x over previous
//
#include <hip/hip_runtime.h>

typedef __attribute__((ext_vector_type(8))) short bf16x8;
typedef __attribute__((ext_vector_type(4))) float f32x4;

#define NROWS   65536
#define NSLICE  8
#define SLICESZ 4160
#define SETSZ   (NSLICE*SLICESZ)   // 33280 floats per iteration set
#define EPSV    1e-8f
#define RPITCH  264                 // rLT row pitch in halfwords (+8 pad)

#define KB      512                 // kmeans blocks (2/CU), 128 rows each
#define RPB     128                 // rows per kmeans block

// ---- ws layout (float offsets) ----
#define WS_DEC   0
#define WS_LOSS  1
#define WS_SETS  16                          // 9 sets (iters 0..8 write)
#define WS_X2    (WS_SETS + 9*SETSZ)         // 299536
#define WS_ENCB  (WS_X2 + NROWS)             // 365072
#define WS_EBF   (WS_ENCB + 2097152)
#define WS_END   (WS_EBF + 2097152)          // ~18.3 MB

static __device__ __forceinline__ unsigned short f2bf(float f) {
    union { float f; unsigned u; } v; v.f = f;
    unsigned u = v.u + 0x7fffu + ((v.u >> 16) & 1u);
    return (unsigned short)(u >> 16);
}
static __device__ __forceinline__ float bf2f(unsigned short h) {
    union { unsigned u; float f; } v; v.u = ((unsigned)h) << 16; return v.f;
}
static __device__ __forceinline__ uint4 pack8(const unsigned short* h) {
    uint4 o;
    o.x = h[0] | ((unsigned)h[1] << 16);
    o.y = h[2] | ((unsigned)h[3] << 16);
    o.z = h[4] | ((unsigned)h[5] << 16);
    o.w = h[6] | ((unsigned)h[7] << 16);
    return o;
}

// ---------------------------------------------------------------------------
// Decoder loss, standalone.  REGULAR cached float4 loads (NT loads bypassed
// L2/L3 and capped the stream at ~2.3 TB/s; cached f32x4 streaming measures
// ~6.3 TB/s on this chip).  2048 blocks x 256 threads = 524288 threads;
// each array is 8388608 f32x4 -> exactly 16 f32x4 per thread (4 iters x 4).
// ---------------------------------------------------------------------------
__global__ __launch_bounds__(256, 4) void decoder_loss_kernel(
    const f32x4* __restrict__ X4, const f32x4* __restrict__ D4,
    float* __restrict__ out_sum)
{
    const size_t tid = (size_t)blockIdx.x * 256 + threadIdx.x;   // 0..524287
    float s0 = 0.f, s1 = 0.f, s2 = 0.f, s3 = 0.f;
    #pragma unroll
    for (int i = 0; i < 4; ++i) {
        f32x4 xv[4], dv[4];
        #pragma unroll
        for (int j = 0; j < 4; ++j) xv[j] = X4[tid + (size_t)(i * 4 + j) * 524288];
        #pragma unroll
        for (int j = 0; j < 4; ++j) dv[j] = D4[tid + (size_t)(i * 4 + j) * 524288];
        #pragma unroll
        for (int j = 0; j < 4; ++j) {
            f32x4 d = xv[j] - dv[j];
            s0 = fmaf(d.x, d.x, s0); s1 = fmaf(d.y, d.y, s1);
            s2 = fmaf(d.z, d.z, s2); s3 = fmaf(d.w, d.w, s3);
        }
    }
    float s = (s0 + s1) + (s2 + s3);
    #pragma unroll
    for (int off = 32; off; off >>= 1) s += __shfl_down(s, off, 64);
    __shared__ float red[4];
    if ((threadIdx.x & 63) == 0) red[threadIdx.x >> 6] = s;
    __syncthreads();
    if (threadIdx.x == 0) atomicAdd(out_sum, red[0] + red[1] + red[2] + red[3]);
}

// ---------------------------------------------------------------------------
// prep0: enc f32 -> encB (bf16 row-major), encBfrag (phase-2 B fragment
// order), x2[row] = |bf16(enc_row)|^2.  Grid 1024 x 256, 64 rows/block.
// ---------------------------------------------------------------------------
__global__ __launch_bounds__(256) void prep0(
    const float* __restrict__ enc, unsigned* __restrict__ encB,
    uint4* __restrict__ encBfrag, float* __restrict__ x2)
{
    __shared__ unsigned short L[64 * 64];
    int t = threadIdx.x;
    int rl = t >> 2, part = t & 3;
    int row = blockIdx.x * 64 + rl;
    const float4* src = (const float4*)(enc + (size_t)row * 64 + part * 16);
    unsigned short hv[16];
    float ss = 0.f;
    #pragma unroll
    for (int i = 0; i < 4; ++i) {
        float4 v = src[i];
        unsigned short a = f2bf(v.x), b = f2bf(v.y), c = f2bf(v.z), d = f2bf(v.w);
        hv[i*4+0] = a; hv[i*4+1] = b; hv[i*4+2] = c; hv[i*4+3] = d;
        float fa = bf2f(a), fb = bf2f(b), fc = bf2f(c), fd = bf2f(d);
        ss = fmaf(fa, fa, fmaf(fb, fb, fmaf(fc, fc, fmaf(fd, fd, ss))));
    }
    unsigned* dst = encB + ((size_t)row * 64 + part * 16) / 2;
    #pragma unroll
    for (int i = 0; i < 8; ++i) dst[i] = (unsigned)hv[2*i] | ((unsigned)hv[2*i+1] << 16);
    #pragma unroll
    for (int i = 0; i < 16; ++i) L[rl * 64 + part * 16 + i] = hv[i];
    ss += __shfl_xor(ss, 1, 64);
    ss += __shfl_xor(ss, 2, 64);
    if (part == 0) x2[row] = ss;
    __syncthreads();
    for (int e = t; e < 512; e += 256) {
        int rbl = e >> 8, dt = (e >> 6) & 3, lane = e & 63;
        int q = lane >> 4, c = lane & 15;
        unsigned short hw[8];
        #pragma unroll
        for (int j = 0; j < 8; ++j)
            hw[j] = L[(rbl * 32 + q * 8 + j) * 64 + dt * 16 + c];
        encBfrag[(size_t)blockIdx.x * 512 + e] = pack8(hw);
    }
}

// ---------------------------------------------------------------------------
// Fused k-means iteration, 512 blocks x 128 rows (2 blocks/CU = 2 waves/SIMD
// so co-resident blocks hide each other's barrier drains and shuffle/LDS
// latency — the 256-block version ran at 1 wave/SIMD, fully exposed).
//  prologue: build C (bf16) from prev set / enc, c2 via shuffle reduce
//  phase 1 : one 128-row pass: S = enc@C^T (mfma), softmax, r -> LDS
//  phase 2 : wave w owns k-rows mt=w, 4 row-subtiles, global atomics
// ---------------------------------------------------------------------------
__global__ __launch_bounds__(256, 2) void kmeans_main(
    const bf16x8* __restrict__ encB8, const bf16x8* __restrict__ encBfrag8,
    const float* __restrict__ enc, const float* __restrict__ prev_set,
    float* __restrict__ cur_set, const float* __restrict__ x2,
    float* __restrict__ loss_sum, int mode)
{
    __shared__ union {
        unsigned short CsBf[4096];        // prologue: bf16 C[k][d]
        unsigned short rLT[64 * RPITCH];  // phase 1/2: r^T  [k][row_local]
    } U;
    __shared__ float x2L[RPB];
    __shared__ float c2L[64];
    __shared__ float rslL[64];
    __shared__ float rsumL[64];
    __shared__ float lredL[4];

    const int t = threadIdx.x;
    const int wave = t >> 6, lane = t & 63, q = lane >> 4, c = lane & 15;
    const int blockR0 = blockIdx.x * RPB;

    // ---- prologue ----
    if (t < RPB) x2L[t] = x2[blockR0 + t];
    if (t < 64) {
        rsumL[t] = 0.f;
        float v = 0.f;
        if (mode != 0) {
            #pragma unroll
            for (int sl = 0; sl < NSLICE; ++sl)
                v += prev_set[sl * SLICESZ + 4096 + t];
        }
        rslL[t] = 1.f / (v + EPSV);
    }
    __syncthreads();

    float c2part[4];
    #pragma unroll
    for (int j = 0; j < 4; ++j) {
        int v4 = t + j * 256;      // f32x4 index into C (1024 total)
        int row = v4 >> 4;
        float vx, vy, vz, vw;
        if (mode == 0) {
            f32x4 e = ((const f32x4*)enc)[v4];
            vx = e.x; vy = e.y; vz = e.z; vw = e.w;
        } else {
            float sx = 0.f, sy = 0.f, sz = 0.f, sw = 0.f;
            #pragma unroll
            for (int sl = 0; sl < NSLICE; ++sl) {
                f32x4 u = ((const f32x4*)(prev_set + (size_t)sl * SLICESZ))[v4];
                sx += u.x; sy += u.y; sz += u.z; sw += u.w;
            }
            float inv = rslL[row];
            vx = sx * inv; vy = sy * inv; vz = sz * inv; vw = sw * inv;
        }
        ushort4 h;
        h.x = f2bf(vx); h.y = f2bf(vy); h.z = f2bf(vz); h.w = f2bf(vw);
        ((ushort4*)U.CsBf)[v4] = h;
        float fx = bf2f(h.x), fy = bf2f(h.y), fz = bf2f(h.z), fw = bf2f(h.w);
        c2part[j] = fmaf(fx, fx, fmaf(fy, fy, fmaf(fz, fz, fw * fw)));
    }
    #pragma unroll
    for (int j = 0; j < 4; ++j) {
        float p = c2part[j];
        p += __shfl_xor(p, 1, 64); p += __shfl_xor(p, 2, 64);
        p += __shfl_xor(p, 4, 64); p += __shfl_xor(p, 8, 64);
        if ((lane & 15) == 0) c2L[j * 16 + (t >> 4)] = p;
    }
    __syncthreads();

    bf16x8 bfr[2][4];
    #pragma unroll
    for (int kk2 = 0; kk2 < 2; ++kk2)
        #pragma unroll
        for (int nt = 0; nt < 4; ++nt)
            bfr[kk2][nt] = *(const bf16x8*)&U.CsBf[(nt * 16 + c) * 64 + kk2 * 32 + q * 8];
    float c2f[4];
    #pragma unroll
    for (int nt = 0; nt < 4; ++nt) c2f[nt] = c2L[nt * 16 + c];
    __syncthreads();   // CsBf dead; U.rLT may now be written

    // ---- phase 1 (+softmax), one pass of 128 rows ----
    const f32x4 z4 = {0.f, 0.f, 0.f, 0.f};
    float rs[4] = {0.f, 0.f, 0.f, 0.f};
    float lossacc = 0.f;
    {
        bf16x8 a2f[4];
        #pragma unroll
        for (int sub = 0; sub < 2; ++sub) {
            int arow = blockR0 + wave * 32 + 8 * (c >> 2) + sub * 4 + (c & 3);
            const bf16x8* ap = encB8 + (size_t)arow * 8 + q;
            bf16x8 a0 = ap[0], a1 = ap[4];
            f32x4 accf[4];
            #pragma unroll
            for (int nt = 0; nt < 4; ++nt) {
                f32x4 s = __builtin_amdgcn_mfma_f32_16x16x32_bf16(a0, bfr[0][nt], z4, 0, 0, 0);
                accf[nt]  = __builtin_amdgcn_mfma_f32_16x16x32_bf16(a1, bfr[1][nt], s,  0, 0, 0);
            }
            #pragma unroll
            for (int reg = 0; reg < 4; ++reg) {
                int rloc = wave * 32 + 8 * q + sub * 4 + reg;
                float x2r = x2L[rloc];
                float d2[4], mn = 3.4e38f;
                #pragma unroll
                for (int nt = 0; nt < 4; ++nt) {
                    float v = fmaxf(x2r + c2f[nt] - 2.f * accf[nt][reg], 0.f);
                    d2[nt] = v; mn = fminf(mn, v);
                }
                mn = fminf(mn, __shfl_xor(mn, 1, 64));
                mn = fminf(mn, __shfl_xor(mn, 2, 64));
                mn = fminf(mn, __shfl_xor(mn, 4, 64));
                mn = fminf(mn, __shfl_xor(mn, 8, 64));
                float e[4], s = 0.f, swd = 0.f;
                #pragma unroll
                for (int nt = 0; nt < 4; ++nt) {
                    float ev = __expf(mn - d2[nt]);
                    e[nt] = ev; s += ev; swd = fmaf(ev, d2[nt], swd);
                }
                s   += __shfl_xor(s, 1, 64);   swd += __shfl_xor(swd, 1, 64);
                s   += __shfl_xor(s, 2, 64);   swd += __shfl_xor(swd, 2, 64);
                s   += __shfl_xor(s, 4, 64);   swd += __shfl_xor(swd, 4, 64);
                s   += __shfl_xor(s, 8, 64);   swd += __shfl_xor(swd, 8, 64);
                float inv = 1.f / s;
                if (mode == 2 && c == 0) lossacc += swd * inv;
                #pragma unroll
                for (int nt = 0; nt < 4; ++nt) {
                    float rv = e[nt] * inv;
                    rs[nt] += rv;
                    a2f[nt][sub * 4 + reg] = (short)f2bf(rv);
                }
            }
        }
        if (mode != 2) {
            #pragma unroll
            for (int nt = 0; nt < 4; ++nt)
                *(bf16x8*)&U.rLT[(nt * 16 + c) * RPITCH + wave * 32 + 8 * q] = a2f[nt];
        }
    }

    if (mode != 2) {
        #pragma unroll
        for (int nt = 0; nt < 4; ++nt) {
            float v = rs[nt];
            v += __shfl_xor(v, 16, 64);
            v += __shfl_xor(v, 32, 64);
            if (q == 0) atomicAdd(&rsumL[nt * 16 + c], v);
        }
        __syncthreads();   // rLT visible, rsumL complete

        // ---- phase 2: wave owns k-rows mt=wave, 4 row-subtiles ----
        const int mt = wave;
        f32x4 cacc[4];
        #pragma unroll
        for (int dt = 0; dt < 4; ++dt) cacc[dt] = z4;
        #pragma unroll
        for (int kk = 0; kk < 4; ++kk) {
            bf16x8 aA = *(const bf16x8*)&U.rLT[(mt * 16 + c) * RPITCH + kk * 32 + q * 8];
            #pragma unroll
            for (int dt = 0; dt < 4; ++dt) {
                bf16x8 bB = encBfrag8[((size_t)(blockIdx.x * 4 + kk) * 4 + dt) * 64 + lane];
                cacc[dt] = __builtin_amdgcn_mfma_f32_16x16x32_bf16(aA, bB, cacc[dt], 0, 0, 0);
            }
        }
        float* slice = cur_set + (size_t)(blockIdx.x & (NSLICE - 1)) * SLICESZ;
        #pragma unroll
        for (int dt = 0; dt < 4; ++dt)
            #pragma unroll
            for (int reg = 0; reg < 4; ++reg)
                atomicAdd(&slice[(mt * 16 + q * 4 + reg) * 64 + dt * 16 + c],
                          cacc[dt][reg]);
        if (t < 64) atomicAdd(&slice[4096 + t], rsumL[t]);
    } else {
        #pragma unroll
        for (int off = 32; off; off >>= 1) lossacc += __shfl_down(lossacc, off, 64);
        if (lane == 0) lredL[wave] = lossacc;
        __syncthreads();
        if (t == 0) atomicAdd(loss_sum, lredL[0] + lredL[1] + lredL[2] + lredL[3]);
    }
}

// ---------------------------------------------------------------------------
__global__ void finalize_kernel(const float* __restrict__ dec_sum,
                                const float* __restrict__ loss_sum,
                                float* __restrict__ out)
{
    out[0] = dec_sum[0] * (1.f / (65536.f * 512.f))
           + 0.001f * (loss_sum[0] * (1.f / 65536.f));
}

// ---------------------------------------------------------------------------
extern "C" void kernel_launch(void* const* d_in, const int* in_sizes, int n_in,
                              void* d_out, int out_size, void* d_ws, size_t ws_size,
                              hipStream_t stream)
{
    const float* X   = (const float*)d_in[0];
    const float* enc = (const float*)d_in[1];
    const float* dec = (const float*)d_in[2];

    float* ws = (float*)d_ws;
    float* dec_sum  = ws + WS_DEC;
    float* loss_sum = ws + WS_LOSS;
    float* sets = ws + WS_SETS;
    float* x2   = ws + WS_X2;
    unsigned* encB  = (unsigned*)(ws + WS_ENCB);
    uint4* encBfrag = (uint4*)(ws + WS_EBF);

    hipMemsetAsync(d_ws, 0, (size_t)WS_X2 * sizeof(float), stream);

    prep0<<<dim3(1024), dim3(256), 0, stream>>>(enc, encB, encBfrag, x2);

    const bf16x8* encB8 = (const bf16x8*)encB;
    const bf16x8* eBf8  = (const bf16x8*)encBfrag;

    for (int it = 0; it < 10; ++it) {
        int mode = (it == 0) ? 0 : ((it == 9) ? 2 : 1);
        const float* prev = (it == 0) ? sets : sets + (size_t)(it - 1) * SETSZ;
        float* cur = (it < 9) ? sets + (size_t)it * SETSZ : sets;
        kmeans_main<<<dim3(KB), dim3(256), 0, stream>>>(
            encB8, eBf8, enc, prev, cur, x2, loss_sum, mode);
    }

    // Decoder last: its 268 MB stream can't evict the kmeans working set.
    decoder_loss_kernel<<<dim3(2048), dim3(256), 0, stream>>>(
        (const f32x4*)X, (const f32x4*)dec, dec_sum);

    finalize_kernel<<<1, 1, 0, stream>>>(dec_sum, loss_sum, (float*)d_out);
}

// Round 6
// 458.621 us; speedup vs baseline: 1.1067x; 1.0089x over previous
//
#include <hip/hip_runtime.h>

typedef __attribute__((ext_vector_type(8))) short bf16x8;
typedef __attribute__((ext_vector_type(4))) float f32x4;

#define NROWS   65536
#define NSLICE  8
#define SLICESZ 4160
#define SETSZ   (NSLICE*SLICESZ)   // 33280 floats per iteration set
#define EPSV    1e-8f
#define RPITCH  264                 // rLT row pitch in halfwords (+8 pad)

#define KB      512                 // kmeans blocks (2/CU), 128 rows each
#define RPB     128                 // rows per kmeans block

// ---- ws layout (float offsets) ----
#define WS_DEC   0
#define WS_LOSS  1
#define WS_SETS  16                          // 9 sets (iters 0..8 write)
#define WS_X2    (WS_SETS + 9*SETSZ)         // 299536
#define WS_ENCB  (WS_X2 + NROWS)             // 365072
#define WS_EBF   (WS_ENCB + 2097152)
#define WS_END   (WS_EBF + 2097152)          // ~18.3 MB

static __device__ __forceinline__ unsigned short f2bf(float f) {
    union { float f; unsigned u; } v; v.f = f;
    unsigned u = v.u + 0x7fffu + ((v.u >> 16) & 1u);
    return (unsigned short)(u >> 16);
}
static __device__ __forceinline__ float bf2f(unsigned short h) {
    union { unsigned u; float f; } v; v.u = ((unsigned)h) << 16; return v.f;
}
static __device__ __forceinline__ uint4 pack8(const unsigned short* h) {
    uint4 o;
    o.x = h[0] | ((unsigned)h[1] << 16);
    o.y = h[2] | ((unsigned)h[3] << 16);
    o.z = h[4] | ((unsigned)h[5] << 16);
    o.w = h[6] | ((unsigned)h[7] << 16);
    return o;
}

// ---------------------------------------------------------------------------
// Decoder loss, standalone, WAVE-CONTIGUOUS addressing.
// Every prior variant strode power-of-2 MB between a wave's consecutive
// loads (32MB/8MB/1MB) and all capped at ~2.3-2.7 TB/s regardless of
// NT/cached or HBM/L3 residency — a chip-level pattern penalty (no DRAM
// row locality), not a per-CU limit (Little's law supports >150 GB/s/CU
// even with 2 loads in flight).  Here each wave sweeps a CONTIGUOUS 16 KB
// of X and of D: 8192 waves x 1024 f32x4; instruction k reads
// [wave*16KB + k*1KB + lane*16B] — the 6.3 TB/s copy-bench pattern.
// ---------------------------------------------------------------------------
__global__ __launch_bounds__(256, 4) void decoder_loss_kernel(
    const f32x4* __restrict__ X4, const f32x4* __restrict__ D4,
    float* __restrict__ out_sum)
{
    const int wgid = blockIdx.x * 4 + (threadIdx.x >> 6);   // 0..8191
    const int lane = threadIdx.x & 63;
    const size_t base = (size_t)wgid * 1024 + lane;         // f32x4 units
    float s0 = 0.f, s1 = 0.f, s2 = 0.f, s3 = 0.f;
    #pragma unroll
    for (int i = 0; i < 4; ++i) {
        f32x4 xv[4], dv[4];
        #pragma unroll
        for (int j = 0; j < 4; ++j) xv[j] = X4[base + (size_t)(i * 4 + j) * 64];
        #pragma unroll
        for (int j = 0; j < 4; ++j) dv[j] = D4[base + (size_t)(i * 4 + j) * 64];
        #pragma unroll
        for (int j = 0; j < 4; ++j) {
            f32x4 d = xv[j] - dv[j];
            s0 = fmaf(d.x, d.x, s0); s1 = fmaf(d.y, d.y, s1);
            s2 = fmaf(d.z, d.z, s2); s3 = fmaf(d.w, d.w, s3);
        }
    }
    float s = (s0 + s1) + (s2 + s3);
    #pragma unroll
    for (int off = 32; off; off >>= 1) s += __shfl_down(s, off, 64);
    __shared__ float red[4];
    if ((threadIdx.x & 63) == 0) red[threadIdx.x >> 6] = s;
    __syncthreads();
    if (threadIdx.x == 0) atomicAdd(out_sum, red[0] + red[1] + red[2] + red[3]);
}

// ---------------------------------------------------------------------------
// prep0: enc f32 -> encB (bf16 row-major), encBfrag (phase-2 B fragment
// order), x2[row] = |bf16(enc_row)|^2.  Grid 1024 x 256, 64 rows/block.
// ---------------------------------------------------------------------------
__global__ __launch_bounds__(256) void prep0(
    const float* __restrict__ enc, unsigned* __restrict__ encB,
    uint4* __restrict__ encBfrag, float* __restrict__ x2)
{
    __shared__ unsigned short L[64 * 64];
    int t = threadIdx.x;
    int rl = t >> 2, part = t & 3;
    int row = blockIdx.x * 64 + rl;
    const float4* src = (const float4*)(enc + (size_t)row * 64 + part * 16);
    unsigned short hv[16];
    float ss = 0.f;
    #pragma unroll
    for (int i = 0; i < 4; ++i) {
        float4 v = src[i];
        unsigned short a = f2bf(v.x), b = f2bf(v.y), c = f2bf(v.z), d = f2bf(v.w);
        hv[i*4+0] = a; hv[i*4+1] = b; hv[i*4+2] = c; hv[i*4+3] = d;
        float fa = bf2f(a), fb = bf2f(b), fc = bf2f(c), fd = bf2f(d);
        ss = fmaf(fa, fa, fmaf(fb, fb, fmaf(fc, fc, fmaf(fd, fd, ss))));
    }
    unsigned* dst = encB + ((size_t)row * 64 + part * 16) / 2;
    #pragma unroll
    for (int i = 0; i < 8; ++i) dst[i] = (unsigned)hv[2*i] | ((unsigned)hv[2*i+1] << 16);
    #pragma unroll
    for (int i = 0; i < 16; ++i) L[rl * 64 + part * 16 + i] = hv[i];
    ss += __shfl_xor(ss, 1, 64);
    ss += __shfl_xor(ss, 2, 64);
    if (part == 0) x2[row] = ss;
    __syncthreads();
    for (int e = t; e < 512; e += 256) {
        int rbl = e >> 8, dt = (e >> 6) & 3, lane = e & 63;
        int q = lane >> 4, c = lane & 15;
        unsigned short hw[8];
        #pragma unroll
        for (int j = 0; j < 8; ++j)
            hw[j] = L[(rbl * 32 + q * 8 + j) * 64 + dt * 16 + c];
        encBfrag[(size_t)blockIdx.x * 512 + e] = pack8(hw);
    }
}

// ---------------------------------------------------------------------------
// Fused k-means iteration, 512 blocks x 128 rows (2 blocks/CU).
//  prologue: build C (bf16) from prev set / enc, c2 via shuffle reduce
//  phase 1 : one 128-row pass: S = enc@C^T (mfma), softmax, r -> LDS
//  phase 2 : wave w owns k-rows mt=w, 4 row-subtiles, global atomics
// ---------------------------------------------------------------------------
__global__ __launch_bounds__(256, 2) void kmeans_main(
    const bf16x8* __restrict__ encB8, const bf16x8* __restrict__ encBfrag8,
    const float* __restrict__ enc, const float* __restrict__ prev_set,
    float* __restrict__ cur_set, const float* __restrict__ x2,
    float* __restrict__ loss_sum, int mode)
{
    __shared__ union {
        unsigned short CsBf[4096];        // prologue: bf16 C[k][d]
        unsigned short rLT[64 * RPITCH];  // phase 1/2: r^T  [k][row_local]
    } U;
    __shared__ float x2L[RPB];
    __shared__ float c2L[64];
    __shared__ float rslL[64];
    __shared__ float rsumL[64];
    __shared__ float lredL[4];

    const int t = threadIdx.x;
    const int wave = t >> 6, lane = t & 63, q = lane >> 4, c = lane & 15;
    const int blockR0 = blockIdx.x * RPB;

    // ---- prologue ----
    if (t < RPB) x2L[t] = x2[blockR0 + t];
    if (t < 64) {
        rsumL[t] = 0.f;
        float v = 0.f;
        if (mode != 0) {
            #pragma unroll
            for (int sl = 0; sl < NSLICE; ++sl)
                v += prev_set[sl * SLICESZ + 4096 + t];
        }
        rslL[t] = 1.f / (v + EPSV);
    }
    __syncthreads();

    float c2part[4];
    #pragma unroll
    for (int j = 0; j < 4; ++j) {
        int v4 = t + j * 256;      // f32x4 index into C (1024 total)
        int row = v4 >> 4;
        float vx, vy, vz, vw;
        if (mode == 0) {
            f32x4 e = ((const f32x4*)enc)[v4];
            vx = e.x; vy = e.y; vz = e.z; vw = e.w;
        } else {
            float sx = 0.f, sy = 0.f, sz = 0.f, sw = 0.f;
            #pragma unroll
            for (int sl = 0; sl < NSLICE; ++sl) {
                f32x4 u = ((const f32x4*)(prev_set + (size_t)sl * SLICESZ))[v4];
                sx += u.x; sy += u.y; sz += u.z; sw += u.w;
            }
            float inv = rslL[row];
            vx = sx * inv; vy = sy * inv; vz = sz * inv; vw = sw * inv;
        }
        ushort4 h;
        h.x = f2bf(vx); h.y = f2bf(vy); h.z = f2bf(vz); h.w = f2bf(vw);
        ((ushort4*)U.CsBf)[v4] = h;
        float fx = bf2f(h.x), fy = bf2f(h.y), fz = bf2f(h.z), fw = bf2f(h.w);
        c2part[j] = fmaf(fx, fx, fmaf(fy, fy, fmaf(fz, fz, fw * fw)));
    }
    #pragma unroll
    for (int j = 0; j < 4; ++j) {
        float p = c2part[j];
        p += __shfl_xor(p, 1, 64); p += __shfl_xor(p, 2, 64);
        p += __shfl_xor(p, 4, 64); p += __shfl_xor(p, 8, 64);
        if ((lane & 15) == 0) c2L[j * 16 + (t >> 4)] = p;
    }
    __syncthreads();

    bf16x8 bfr[2][4];
    #pragma unroll
    for (int kk2 = 0; kk2 < 2; ++kk2)
        #pragma unroll
        for (int nt = 0; nt < 4; ++nt)
            bfr[kk2][nt] = *(const bf16x8*)&U.CsBf[(nt * 16 + c) * 64 + kk2 * 32 + q * 8];
    float c2f[4];
    #pragma unroll
    for (int nt = 0; nt < 4; ++nt) c2f[nt] = c2L[nt * 16 + c];
    __syncthreads();   // CsBf dead; U.rLT may now be written

    // ---- phase 1 (+softmax), one pass of 128 rows ----
    const f32x4 z4 = {0.f, 0.f, 0.f, 0.f};
    float rs[4] = {0.f, 0.f, 0.f, 0.f};
    float lossacc = 0.f;
    {
        bf16x8 a2f[4];
        #pragma unroll
        for (int sub = 0; sub < 2; ++sub) {
            int arow = blockR0 + wave * 32 + 8 * (c >> 2) + sub * 4 + (c & 3);
            const bf16x8* ap = encB8 + (size_t)arow * 8 + q;
            bf16x8 a0 = ap[0], a1 = ap[4];
            f32x4 accf[4];
            #pragma unroll
            for (int nt = 0; nt < 4; ++nt) {
                f32x4 s = __builtin_amdgcn_mfma_f32_16x16x32_bf16(a0, bfr[0][nt], z4, 0, 0, 0);
                accf[nt]  = __builtin_amdgcn_mfma_f32_16x16x32_bf16(a1, bfr[1][nt], s,  0, 0, 0);
            }
            #pragma unroll
            for (int reg = 0; reg < 4; ++reg) {
                int rloc = wave * 32 + 8 * q + sub * 4 + reg;
                float x2r = x2L[rloc];
                float d2[4], mn = 3.4e38f;
                #pragma unroll
                for (int nt = 0; nt < 4; ++nt) {
                    float v = fmaxf(x2r + c2f[nt] - 2.f * accf[nt][reg], 0.f);
                    d2[nt] = v; mn = fminf(mn, v);
                }
                mn = fminf(mn, __shfl_xor(mn, 1, 64));
                mn = fminf(mn, __shfl_xor(mn, 2, 64));
                mn = fminf(mn, __shfl_xor(mn, 4, 64));
                mn = fminf(mn, __shfl_xor(mn, 8, 64));
                float e[4], s = 0.f, swd = 0.f;
                #pragma unroll
                for (int nt = 0; nt < 4; ++nt) {
                    float ev = __expf(mn - d2[nt]);
                    e[nt] = ev; s += ev; swd = fmaf(ev, d2[nt], swd);
                }
                s   += __shfl_xor(s, 1, 64);   swd += __shfl_xor(swd, 1, 64);
                s   += __shfl_xor(s, 2, 64);   swd += __shfl_xor(swd, 2, 64);
                s   += __shfl_xor(s, 4, 64);   swd += __shfl_xor(swd, 4, 64);
                s   += __shfl_xor(s, 8, 64);   swd += __shfl_xor(swd, 8, 64);
                float inv = 1.f / s;
                if (mode == 2 && c == 0) lossacc += swd * inv;
                #pragma unroll
                for (int nt = 0; nt < 4; ++nt) {
                    float rv = e[nt] * inv;
                    rs[nt] += rv;
                    a2f[nt][sub * 4 + reg] = (short)f2bf(rv);
                }
            }
        }
        if (mode != 2) {
            #pragma unroll
            for (int nt = 0; nt < 4; ++nt)
                *(bf16x8*)&U.rLT[(nt * 16 + c) * RPITCH + wave * 32 + 8 * q] = a2f[nt];
        }
    }

    if (mode != 2) {
        #pragma unroll
        for (int nt = 0; nt < 4; ++nt) {
            float v = rs[nt];
            v += __shfl_xor(v, 16, 64);
            v += __shfl_xor(v, 32, 64);
            if (q == 0) atomicAdd(&rsumL[nt * 16 + c], v);
        }
        __syncthreads();   // rLT visible, rsumL complete

        // ---- phase 2: wave owns k-rows mt=wave, 4 row-subtiles ----
        const int mt = wave;
        f32x4 cacc[4];
        #pragma unroll
        for (int dt = 0; dt < 4; ++dt) cacc[dt] = z4;
        #pragma unroll
        for (int kk = 0; kk < 4; ++kk) {
            bf16x8 aA = *(const bf16x8*)&U.rLT[(mt * 16 + c) * RPITCH + kk * 32 + q * 8];
            #pragma unroll
            for (int dt = 0; dt < 4; ++dt) {
                bf16x8 bB = encBfrag8[((size_t)(blockIdx.x * 4 + kk) * 4 + dt) * 64 + lane];
                cacc[dt] = __builtin_amdgcn_mfma_f32_16x16x32_bf16(aA, bB, cacc[dt], 0, 0, 0);
            }
        }
        float* slice = cur_set + (size_t)(blockIdx.x & (NSLICE - 1)) * SLICESZ;
        #pragma unroll
        for (int dt = 0; dt < 4; ++dt)
            #pragma unroll
            for (int reg = 0; reg < 4; ++reg)
                atomicAdd(&slice[(mt * 16 + q * 4 + reg) * 64 + dt * 16 + c],
                          cacc[dt][reg]);
        if (t < 64) atomicAdd(&slice[4096 + t], rsumL[t]);
    } else {
        #pragma unroll
        for (int off = 32; off; off >>= 1) lossacc += __shfl_down(lossacc, off, 64);
        if (lane == 0) lredL[wave] = lossacc;
        __syncthreads();
        if (t == 0) atomicAdd(loss_sum, lredL[0] + lredL[1] + lredL[2] + lredL[3]);
    }
}

// ---------------------------------------------------------------------------
__global__ void finalize_kernel(const float* __restrict__ dec_sum,
                                const float* __restrict__ loss_sum,
                                float* __restrict__ out)
{
    out[0] = dec_sum[0] * (1.f / (65536.f * 512.f))
           + 0.001f * (loss_sum[0] * (1.f / 65536.f));
}

// ---------------------------------------------------------------------------
extern "C" void kernel_launch(void* const* d_in, const int* in_sizes, int n_in,
                              void* d_out, int out_size, void* d_ws, size_t ws_size,
                              hipStream_t stream)
{
    const float* X   = (const float*)d_in[0];
    const float* enc = (const float*)d_in[1];
    const float* dec = (const float*)d_in[2];

    float* ws = (float*)d_ws;
    float* dec_sum  = ws + WS_DEC;
    float* loss_sum = ws + WS_LOSS;
    float* sets = ws + WS_SETS;
    float* x2   = ws + WS_X2;
    unsigned* encB  = (unsigned*)(ws + WS_ENCB);
    uint4* encBfrag = (uint4*)(ws + WS_EBF);

    hipMemsetAsync(d_ws, 0, (size_t)WS_X2 * sizeof(float), stream);

    prep0<<<dim3(1024), dim3(256), 0, stream>>>(enc, encB, encBfrag, x2);

    const bf16x8* encB8 = (const bf16x8*)encB;
    const bf16x8* eBf8  = (const bf16x8*)encBfrag;

    for (int it = 0; it < 10; ++it) {
        int mode = (it == 0) ? 0 : ((it == 9) ? 2 : 1);
        const float* prev = (it == 0) ? sets : sets + (size_t)(it - 1) * SETSZ;
        float* cur = (it < 9) ? sets + (size_t)it * SETSZ : sets;
        kmeans_main<<<dim3(KB), dim3(256), 0, stream>>>(
            encB8, eBf8, enc, prev, cur, x2, loss_sum, mode);
    }

    // Decoder last: its 268 MB stream can't evict the kmeans working set.
    decoder_loss_kernel<<<dim3(2048), dim3(256), 0, stream>>>(
        (const f32x4*)X, (const f32x4*)dec, dec_sum);

    finalize_kernel<<<1, 1, 0, stream>>>(dec_sum, loss_sum, (float*)d_out);
}